// Round 19
// baseline (96.435 us; speedup 1.0000x reference)
//
#include <hip/hip_runtime.h>
#include <hip/hip_bf16.h>

#define IN_DIM 256
#define NHEADS 8
#define HDIM 32
#define BATCH 2
#define NTOK 4096
#define QSCALE (0.17677669529663687f * 1.4426950408889634f)

typedef __hip_bfloat16 bf16;
typedef __attribute__((ext_vector_type(8))) short bf16x8;
typedef __attribute__((ext_vector_type(4))) short bf16x4;
typedef __attribute__((ext_vector_type(4))) float f32x4;

union bfrag { bf16x8 v; bf16x4 h[2]; };

__device__ __forceinline__ float b2f(bf16 x) { return __bfloat162float(x); }

#if __has_builtin(__builtin_amdgcn_exp2f)
__device__ __forceinline__ float fast_exp2(float x) { return __builtin_amdgcn_exp2f(x); }
#else
__device__ __forceinline__ float fast_exp2(float x) { return exp2f(x); }
#endif

__device__ __forceinline__ unsigned packbf2(float a, float b) {
    union { __hip_bfloat162 h; unsigned u; } c;
    c.h = __float22bfloat162_rn(float2{a, b});
    return c.u;
}

// pack 16 fp32 -> 16 bf16 into LDS (8B-aligned), as 4 uint2 writes
__device__ __forceinline__ void pack16(float4 a, float4 b, float4 c, float4 d,
                                       bf16* dst) {
    uint2 w0 = {packbf2(a.x, a.y), packbf2(a.z, a.w)};
    uint2 w1 = {packbf2(b.x, b.y), packbf2(b.z, b.w)};
    uint2 w2 = {packbf2(c.x, c.y), packbf2(c.z, c.w)};
    uint2 w3 = {packbf2(d.x, d.y), packbf2(d.z, d.w)};
    *(uint2*)(dst + 0)  = w0;
    *(uint2*)(dst + 4)  = w1;
    *(uint2*)(dst + 8)  = w2;
    *(uint2*)(dst + 12) = w3;
}

// ---------------------------------------------------------------------------
// Kernel A: MFMA QKV projection.  y[b][n][d] = sum_c X[b][c][n] * W[d][c]
// Q pre-scaled by QSCALE; V stored transposed Vt[b][d][n].
// grid (256, 3, 2); block 256 (4 waves).
// ---------------------------------------------------------------------------
__global__ __launch_bounds__(256) void proj_mfma(
    const float* __restrict__ tgt, const float* __restrict__ src,
    const float* __restrict__ Wq, const float* __restrict__ Wk,
    const float* __restrict__ Wv,
    bf16* __restrict__ Qo, bf16* __restrict__ Ko, bf16* __restrict__ Vo)
{
    const int which = blockIdx.y;
    const int dh = blockIdx.z;
    const int b  = blockIdx.x >> 7;
    const int n0 = (blockIdx.x & 127) * 32;
    const float* X = (which == 0) ? tgt : src;
    const float* W = (which == 0) ? Wq : (which == 1 ? Wk : Wv);

    const int tid = threadIdx.x;
    const int wave = tid >> 6, lane = tid & 63;
    const int lg = lane >> 4, lc = lane & 15;
    const int wn = wave & 1, wdq = wave >> 1;

    __shared__ bf16 As[32 * 260];              // [n][c], stride 260
    __shared__ bf16 Ws[2][128 * 36];           // [d][c-step], stride 36

    {
        const float* Xb = X + (size_t)b * IN_DIM * NTOK + n0;
        for (int it = 0; it < 8; ++it) {
            int idx = it * 256 + tid;
            int c = idx >> 3, j4 = idx & 7;
            float4 x = *(const float4*)(Xb + (size_t)c * NTOK + j4 * 4);
            As[(j4 * 4 + 0) * 260 + c] = __float2bfloat16(x.x);
            As[(j4 * 4 + 1) * 260 + c] = __float2bfloat16(x.y);
            As[(j4 * 4 + 2) * 260 + c] = __float2bfloat16(x.z);
            As[(j4 * 4 + 3) * 260 + c] = __float2bfloat16(x.w);
        }
    }
    const int wd = tid >> 1, wc = (tid & 1) * 16;
    const float* Wbase = W + (size_t)(dh * 128 + wd) * IN_DIM + wc;
    {
        float4 a = *(const float4*)(Wbase + 0);
        float4 bb = *(const float4*)(Wbase + 4);
        float4 cc = *(const float4*)(Wbase + 8);
        float4 dd = *(const float4*)(Wbase + 12);
        pack16(a, bb, cc, dd, &Ws[0][wd * 36 + wc]);
    }
    __syncthreads();

    f32x4 acc[4];
    #pragma unroll
    for (int t = 0; t < 4; ++t) acc[t] = f32x4{0.f, 0.f, 0.f, 0.f};

    for (int s = 0; s < 8; ++s) {
        const int c0 = s * 32;
        float4 pa, pb, pc, pd;
        if (s < 7) {
            const float* wn_ = Wbase + (s + 1) * 32;
            pa = *(const float4*)(wn_ + 0);
            pb = *(const float4*)(wn_ + 4);
            pc = *(const float4*)(wn_ + 8);
            pd = *(const float4*)(wn_ + 12);
        }
        bfrag af;
        const bf16* ap = &As[(wn * 16 + lc) * 260 + c0 + lg * 8];
        af.h[0] = *(const bf16x4*)ap;
        af.h[1] = *(const bf16x4*)(ap + 4);
        #pragma unroll
        for (int t = 0; t < 4; ++t) {
            bfrag wf;
            const bf16* wp = &Ws[s & 1][(wdq * 64 + t * 16 + lc) * 36 + lg * 8];
            wf.h[0] = *(const bf16x4*)wp;
            wf.h[1] = *(const bf16x4*)(wp + 4);
            acc[t] = __builtin_amdgcn_mfma_f32_16x16x32_bf16(af.v, wf.v, acc[t], 0, 0, 0);
        }
        if (s < 7) {
            __syncthreads();
            pack16(pa, pb, pc, pd, &Ws[(s + 1) & 1][wd * 36 + wc]);
            __syncthreads();
        }
    }

    const int nb = n0 + wn * 16 + lg * 4;
    if (which == 2) {
        #pragma unroll
        for (int t = 0; t < 4; ++t) {
            int d = dh * 128 + wdq * 64 + t * 16 + lc;
            uint2 pk;
            pk.x = packbf2(acc[t][0], acc[t][1]);
            pk.y = packbf2(acc[t][2], acc[t][3]);
            *(uint2*)(Vo + ((size_t)b * IN_DIM + d) * NTOK + nb) = pk;
        }
    } else {
        const float sc = (which == 0) ? QSCALE : 1.0f;
        bf16* O = (which == 0) ? Qo : Ko;
        #pragma unroll
        for (int t = 0; t < 4; ++t)
            #pragma unroll
            for (int r = 0; r < 4; ++r)
                O[((size_t)b * NTOK + nb + r) * IN_DIM + dh * 128 + wdq * 64 + t * 16 + lc]
                    = __float2bfloat16(acc[t][r] * sc);
    }
}

// ---------------------------------------------------------------------------
// Kernel B: MFMA flash attention, 8 waves, kv-split, QBLK=16, LDS pool-union.
//   - group g = wave>>2 handles kv half [g*2048, g*2048+2048); 64 q/block
//   - no-max softmax => O,l pure sums; group 1 dumps partials to LDS (pool
//     reused AFTER staging reads complete), group 0 adds + epilogue
//   - LDS = 38 KB -> 4 blocks/CU = 32 waves/CU (2x round-18 occupancy)
//   - K=32 slot-merged PV + ones-column l; KL stride 40 / VL stride 72
// grid 1024 (XCD-swizzled); block 512.
// ---------------------------------------------------------------------------
#define KLSZ (64 * 40)
#define VLSZ (32 * 72)
__global__ __launch_bounds__(512) void attn_mfma_kernel(
    const bf16* __restrict__ Q, const bf16* __restrict__ K,
    const bf16* __restrict__ Vt, const float* __restrict__ tgt,
    bf16* __restrict__ Wt)
{
    const int blk = blockIdx.x;
    const int bh  = 2 * (blk & 7) + ((blk >> 3) & 1);
    const int qb  = blk >> 4;               // 0..63
    const int b = bh >> 3, h = bh & 7;
    const int tid  = threadIdx.x;
    const int wave = tid >> 6;
    const int grp  = wave >> 2;             // kv-half
    const int wl   = wave & 3;              // wave within group
    const int lane = tid & 63;
    const int lg = lane >> 4, lc = lane & 15;
    const int qw = qb * 64 + wl * 16;

    // one pool: staging [2 grp][2 buf] K+V; redC overlays it after the loop
    __shared__ __align__(16) char pool[(2 * 2 * (KLSZ + VLSZ)) * 2];  // 38912 B
    bf16* KL = (bf16*)pool;                              // [grp][buf][KLSZ]
    bf16* VL = (bf16*)(pool + 2 * 2 * KLSZ * 2);         // [grp][buf][VLSZ]
    float* redC = (float*)pool;                          // [wl][lane][12] after loop

    const bf16x8 qf = *(const bf16x8*)(Q + ((size_t)b * NTOK + qw + lc) * IN_DIM
                                         + h * HDIM + lg * 8);

    bf16x8 ones8;
    #pragma unroll
    for (int i = 0; i < 8; ++i) ((short*)&ones8)[i] = (short)0x3F80;
    const f32x4 z = {0.f, 0.f, 0.f, 0.f};

    const int tg   = tid & 255;
    const int srow = tg >> 2, sd = (tg & 3) * 8;
    const int vrow = tg >> 3, vch = tg & 7;
    const int kwoff = grp * 2 * KLSZ + srow * 40 + sd;
    const int vwoff = grp * 2 * VLSZ + vrow * 72 + vch * 8;
    const int kroff = grp * 2 * KLSZ + lc * 40 + lg * 8;        // +buf*KLSZ +t*640
    const int vroff0 = grp * 2 * VLSZ + lc * 72 + lg * 4;       // +buf*VLSZ +t*16
    const int vroff1 = grp * 2 * VLSZ + (16 + lc) * 72 + lg * 4;

    const bf16* Kp = K  + ((size_t)b * NTOK + grp * 2048 + srow) * IN_DIM + h * HDIM + sd;
    const bf16* Vp = Vt + ((size_t)b * IN_DIM + h * HDIM + vrow) * NTOK + grp * 2048 + vch * 8;

    f32x4 o0 = {0.f,0.f,0.f,0.f}, o1 = {0.f,0.f,0.f,0.f}, ol = {0.f,0.f,0.f,0.f};

    bf16x8 kreg = *(const bf16x8*)Kp;
    bf16x8 vreg = *(const bf16x8*)Vp;
    Kp += (size_t)64 * IN_DIM;
    Vp += 64;

#define HALF(CUR)                                                              \
    {                                                                          \
        *(bf16x8*)&KL[kwoff + (CUR) * KLSZ] = kreg;                            \
        *(bf16x8*)&VL[vwoff + (CUR) * VLSZ] = vreg;                            \
        kreg = *(const bf16x8*)Kp;                                             \
        vreg = *(const bf16x8*)Vp;                                             \
        Kp += (size_t)64 * IN_DIM;                                             \
        Vp += 64;                                                              \
        __syncthreads();                                                       \
        bf16x8 kf[4];                                                          \
        _Pragma("unroll")                                                      \
        for (int t = 0; t < 4; ++t)                                            \
            kf[t] = *(const bf16x8*)&KL[kroff + (CUR) * KLSZ + t * 640];       \
        bf16x4 v0[4], v1[4];                                                   \
        _Pragma("unroll")                                                      \
        for (int t = 0; t < 4; ++t) {                                          \
            v0[t] = *(const bf16x4*)&VL[vroff0 + (CUR) * VLSZ + t * 16];       \
            v1[t] = *(const bf16x4*)&VL[vroff1 + (CUR) * VLSZ + t * 16];       \
        }                                                                      \
        f32x4 s[4];                                                            \
        __builtin_amdgcn_s_setprio(1);                                         \
        _Pragma("unroll")                                                      \
        for (int t = 0; t < 4; ++t)                                            \
            s[t] = __builtin_amdgcn_mfma_f32_16x16x32_bf16(kf[t], qf, z, 0,0,0); \
        __builtin_amdgcn_s_setprio(0);                                         \
        _Pragma("unroll")                                                      \
        for (int tcp = 0; tcp < 2; ++tcp) {                                    \
            union { bf16x8 v; uint4 u; } pa;                                   \
            pa.u.x = packbf2(fast_exp2(s[2*tcp][0]),   fast_exp2(s[2*tcp][1]));   \
            pa.u.y = packbf2(fast_exp2(s[2*tcp][2]),   fast_exp2(s[2*tcp][3]));   \
            pa.u.z = packbf2(fast_exp2(s[2*tcp+1][0]), fast_exp2(s[2*tcp+1][1])); \
            pa.u.w = packbf2(fast_exp2(s[2*tcp+1][2]), fast_exp2(s[2*tcp+1][3])); \
            bfrag B0, B1;                                                      \
            B0.h[0] = v0[2*tcp]; B0.h[1] = v0[2*tcp+1];                        \
            B1.h[0] = v1[2*tcp]; B1.h[1] = v1[2*tcp+1];                        \
            __builtin_amdgcn_s_setprio(1);                                     \
            o0 = __builtin_amdgcn_mfma_f32_16x16x32_bf16(pa.v, B0.v, o0, 0,0,0); \
            o1 = __builtin_amdgcn_mfma_f32_16x16x32_bf16(pa.v, B1.v, o1, 0,0,0); \
            ol = __builtin_amdgcn_mfma_f32_16x16x32_bf16(pa.v, ones8, ol, 0,0,0); \
            __builtin_amdgcn_s_setprio(0);                                     \
        }                                                                      \
    }

    for (int it = 0; it < NTOK / 256; ++it) {   // 16 iters x 128 kv per group
        HALF(0)
        HALF(1)
    }
#undef HALF

    // ---- combine (pool reuse: all staging reads done after this barrier)
    __syncthreads();
    if (grp) {
        float* d = &redC[(wl * 64 + lane) * 12];
        *(f32x4*)(d + 0) = o0;  *(f32x4*)(d + 4) = o1;  *(f32x4*)(d + 8) = ol;
    }
    __syncthreads();
    if (!grp) {
        const float* s = &redC[(wl * 64 + lane) * 12];
        o0 += *(const f32x4*)(s + 0);
        o1 += *(const f32x4*)(s + 4);
        ol += *(const f32x4*)(s + 8);

        const float* tg0 = tgt + ((size_t)b * IN_DIM + h * HDIM + lc) * NTOK + qw + lg * 4;
        float4 r0 = *(const float4*)tg0;
        float4 r1 = *(const float4*)(tg0 + (size_t)16 * NTOK);

        bf16* op = Wt + ((size_t)b * NTOK + qw + lg * 4) * IN_DIM + h * HDIM + lc;
        #pragma unroll
        for (int r = 0; r < 4; ++r) {
            float inv = 1.f / ol[r];
            op[(size_t)r * IN_DIM]      = __float2bfloat16(o0[r] * inv + (&r0.x)[r]);
            op[(size_t)r * IN_DIM + 16] = __float2bfloat16(o1[r] * inv + (&r1.x)[r]);
        }
    }
}
#undef KLSZ
#undef VLSZ

// ---------------------------------------------------------------------------
// Kernel C: MFMA output projection.  out[b][n][d] = sum_c A[b][n][c]*Wo[d][c]
// ---------------------------------------------------------------------------
__global__ __launch_bounds__(256) void out_mfma(
    const bf16* __restrict__ A, const float* __restrict__ Wo,
    float* __restrict__ out)
{
    const int dh = blockIdx.y;
    const int b  = blockIdx.x >> 7;
    const int n0 = (blockIdx.x & 127) * 32;

    const int tid = threadIdx.x;
    const int wave = tid >> 6, lane = tid & 63;
    const int lg = lane >> 4, lc = lane & 15;
    const int wn = wave & 1, wdq = wave >> 1;

    __shared__ bf16 As[32 * 260];
    __shared__ bf16 Ws[2][128 * 36];

    {
        const bf16* Ab = A + ((size_t)b * NTOK + n0) * IN_DIM;
        for (int it = 0; it < 4; ++it) {
            int idx = it * 256 + tid;
            int r = idx >> 5, ch = idx & 31;
            bfrag v;
            v.v = *(const bf16x8*)(Ab + (size_t)r * IN_DIM + ch * 8);
            *(bf16x4*)&As[r * 260 + ch * 8]     = v.h[0];
            *(bf16x4*)&As[r * 260 + ch * 8 + 4] = v.h[1];
        }
    }
    const int wd = tid >> 1, wc = (tid & 1) * 16;
    const float* Wbase = Wo + (size_t)(dh * 128 + wd) * IN_DIM + wc;
    {
        float4 a = *(const float4*)(Wbase + 0);
        float4 bb = *(const float4*)(Wbase + 4);
        float4 cc = *(const float4*)(Wbase + 8);
        float4 dd = *(const float4*)(Wbase + 12);
        pack16(a, bb, cc, dd, &Ws[0][wd * 36 + wc]);
    }
    __syncthreads();

    f32x4 acc[4];
    #pragma unroll
    for (int t = 0; t < 4; ++t) acc[t] = f32x4{0.f, 0.f, 0.f, 0.f};

    for (int s = 0; s < 8; ++s) {
        const int c0 = s * 32;
        float4 pa, pb, pc, pd;
        if (s < 7) {
            const float* wn_ = Wbase + (s + 1) * 32;
            pa = *(const float4*)(wn_ + 0);
            pb = *(const float4*)(wn_ + 4);
            pc = *(const float4*)(wn_ + 8);
            pd = *(const float4*)(wn_ + 12);
        }
        bfrag af;
        const bf16* ap = &As[(wn * 16 + lc) * 260 + c0 + lg * 8];
        af.h[0] = *(const bf16x4*)ap;
        af.h[1] = *(const bf16x4*)(ap + 4);
        #pragma unroll
        for (int t = 0; t < 4; ++t) {
            bfrag wf;
            const bf16* wp = &Ws[s & 1][(wdq * 64 + t * 16 + lc) * 36 + lg * 8];
            wf.h[0] = *(const bf16x4*)wp;
            wf.h[1] = *(const bf16x4*)(wp + 4);
            acc[t] = __builtin_amdgcn_mfma_f32_16x16x32_bf16(af.v, wf.v, acc[t], 0, 0, 0);
        }
        if (s < 7) {
            __syncthreads();
            pack16(pa, pb, pc, pd, &Ws[(s + 1) & 1][wd * 36 + wc]);
            __syncthreads();
        }
    }

    const int nb = n0 + wn * 16 + lg * 4;
    #pragma unroll
    for (int t = 0; t < 4; ++t)
        #pragma unroll
        for (int r = 0; r < 4; ++r)
            out[((size_t)b * NTOK + nb + r) * IN_DIM + dh * 128 + wdq * 64 + t * 16 + lc]
                = acc[t][r];
}

// ---------------------------------------------------------------------------
extern "C" void kernel_launch(void* const* d_in, const int* in_sizes, int n_in,
                              void* d_out, int out_size, void* d_ws, size_t ws_size,
                              hipStream_t stream) {
    const float* tgt = (const float*)d_in[0];
    const float* src = (const float*)d_in[1];
    const float* Wq  = (const float*)d_in[2];
    const float* Wk  = (const float*)d_in[3];
    const float* Wv  = (const float*)d_in[4];
    const float* Wo  = (const float*)d_in[5];
    float* out = (float*)d_out;

    const size_t SZ = (size_t)BATCH * NTOK * IN_DIM * sizeof(bf16);  // 4 MiB
    char* w = (char*)d_ws;
    bf16* Qb  = (bf16*)(w);
    bf16* Kb  = (bf16*)(w + SZ);
    bf16* Vtb = (bf16*)(w + 2 * SZ);     // transposed V: [B][C][N]
    bf16* Wt  = (bf16*)(w + 3 * SZ);     // attn out + residual, [B][N][C]

    proj_mfma<<<dim3(256, 3, 2), 256, 0, stream>>>(tgt, src, Wq, Wk, Wv, Qb, Kb, Vtb);

    attn_mfma_kernel<<<1024, 512, 0, stream>>>(Qb, Kb, Vtb, tgt, Wt);

    out_mfma<<<dim3(256, 2), 256, 0, stream>>>(Wt, Wo, out);
}

// Round 20
// 83.503 us; speedup vs baseline: 1.1549x; 1.1549x over previous
//
#include <hip/hip_runtime.h>
#include <hip/hip_bf16.h>

#define IN_DIM 256
#define NHEADS 8
#define HDIM 32
#define BATCH 2
#define NTOK 4096
#define QSCALE (0.17677669529663687f * 1.4426950408889634f)

typedef __hip_bfloat16 bf16;
typedef __attribute__((ext_vector_type(8))) short bf16x8;
typedef __attribute__((ext_vector_type(4))) short bf16x4;
typedef __attribute__((ext_vector_type(4))) float f32x4;

union bfrag { bf16x8 v; bf16x4 h[2]; };

__device__ __forceinline__ float b2f(bf16 x) { return __bfloat162float(x); }

#if __has_builtin(__builtin_amdgcn_exp2f)
__device__ __forceinline__ float fast_exp2(float x) { return __builtin_amdgcn_exp2f(x); }
#else
__device__ __forceinline__ float fast_exp2(float x) { return exp2f(x); }
#endif

__device__ __forceinline__ unsigned packbf2(float a, float b) {
    union { __hip_bfloat162 h; unsigned u; } c;
    c.h = __float22bfloat162_rn(float2{a, b});
    return c.u;
}

// pack 16 fp32 -> 16 bf16 into LDS (8B-aligned), as 4 uint2 writes
__device__ __forceinline__ void pack16(float4 a, float4 b, float4 c, float4 d,
                                       bf16* dst) {
    uint2 w0 = {packbf2(a.x, a.y), packbf2(a.z, a.w)};
    uint2 w1 = {packbf2(b.x, b.y), packbf2(b.z, b.w)};
    uint2 w2 = {packbf2(c.x, c.y), packbf2(c.z, c.w)};
    uint2 w3 = {packbf2(d.x, d.y), packbf2(d.z, d.w)};
    *(uint2*)(dst + 0)  = w0;
    *(uint2*)(dst + 4)  = w1;
    *(uint2*)(dst + 8)  = w2;
    *(uint2*)(dst + 12) = w3;
}

// ---------------------------------------------------------------------------
// Kernel A: MFMA QKV projection.  y[b][n][d] = sum_c X[b][c][n] * W[d][c]
// Q pre-scaled by QSCALE; V stored transposed Vt[b][d][n].
// grid (256, 3, 2); block 256 (4 waves).
// ---------------------------------------------------------------------------
__global__ __launch_bounds__(256) void proj_mfma(
    const float* __restrict__ tgt, const float* __restrict__ src,
    const float* __restrict__ Wq, const float* __restrict__ Wk,
    const float* __restrict__ Wv,
    bf16* __restrict__ Qo, bf16* __restrict__ Ko, bf16* __restrict__ Vo)
{
    const int which = blockIdx.y;
    const int dh = blockIdx.z;
    const int b  = blockIdx.x >> 7;
    const int n0 = (blockIdx.x & 127) * 32;
    const float* X = (which == 0) ? tgt : src;
    const float* W = (which == 0) ? Wq : (which == 1 ? Wk : Wv);

    const int tid = threadIdx.x;
    const int wave = tid >> 6, lane = tid & 63;
    const int lg = lane >> 4, lc = lane & 15;
    const int wn = wave & 1, wdq = wave >> 1;

    __shared__ bf16 As[32 * 260];              // [n][c], stride 260
    __shared__ bf16 Ws[2][128 * 36];           // [d][c-step], stride 36

    {
        const float* Xb = X + (size_t)b * IN_DIM * NTOK + n0;
        for (int it = 0; it < 8; ++it) {
            int idx = it * 256 + tid;
            int c = idx >> 3, j4 = idx & 7;
            float4 x = *(const float4*)(Xb + (size_t)c * NTOK + j4 * 4);
            As[(j4 * 4 + 0) * 260 + c] = __float2bfloat16(x.x);
            As[(j4 * 4 + 1) * 260 + c] = __float2bfloat16(x.y);
            As[(j4 * 4 + 2) * 260 + c] = __float2bfloat16(x.z);
            As[(j4 * 4 + 3) * 260 + c] = __float2bfloat16(x.w);
        }
    }
    const int wd = tid >> 1, wc = (tid & 1) * 16;
    const float* Wbase = W + (size_t)(dh * 128 + wd) * IN_DIM + wc;
    {
        float4 a = *(const float4*)(Wbase + 0);
        float4 bb = *(const float4*)(Wbase + 4);
        float4 cc = *(const float4*)(Wbase + 8);
        float4 dd = *(const float4*)(Wbase + 12);
        pack16(a, bb, cc, dd, &Ws[0][wd * 36 + wc]);
    }
    __syncthreads();

    f32x4 acc[4];
    #pragma unroll
    for (int t = 0; t < 4; ++t) acc[t] = f32x4{0.f, 0.f, 0.f, 0.f};

    for (int s = 0; s < 8; ++s) {
        const int c0 = s * 32;
        float4 pa, pb, pc, pd;
        if (s < 7) {
            const float* wn_ = Wbase + (s + 1) * 32;
            pa = *(const float4*)(wn_ + 0);
            pb = *(const float4*)(wn_ + 4);
            pc = *(const float4*)(wn_ + 8);
            pd = *(const float4*)(wn_ + 12);
        }
        bfrag af;
        const bf16* ap = &As[(wn * 16 + lc) * 260 + c0 + lg * 8];
        af.h[0] = *(const bf16x4*)ap;
        af.h[1] = *(const bf16x4*)(ap + 4);
        #pragma unroll
        for (int t = 0; t < 4; ++t) {
            bfrag wf;
            const bf16* wp = &Ws[s & 1][(wdq * 64 + t * 16 + lc) * 36 + lg * 8];
            wf.h[0] = *(const bf16x4*)wp;
            wf.h[1] = *(const bf16x4*)(wp + 4);
            acc[t] = __builtin_amdgcn_mfma_f32_16x16x32_bf16(af.v, wf.v, acc[t], 0, 0, 0);
        }
        if (s < 7) {
            __syncthreads();
            pack16(pa, pb, pc, pd, &Ws[(s + 1) & 1][wd * 36 + wc]);
            __syncthreads();
        }
    }

    const int nb = n0 + wn * 16 + lg * 4;
    if (which == 2) {
        #pragma unroll
        for (int t = 0; t < 4; ++t) {
            int d = dh * 128 + wdq * 64 + t * 16 + lc;
            uint2 pk;
            pk.x = packbf2(acc[t][0], acc[t][1]);
            pk.y = packbf2(acc[t][2], acc[t][3]);
            *(uint2*)(Vo + ((size_t)b * IN_DIM + d) * NTOK + nb) = pk;
        }
    } else {
        const float sc = (which == 0) ? QSCALE : 1.0f;
        bf16* O = (which == 0) ? Qo : Ko;
        #pragma unroll
        for (int t = 0; t < 4; ++t)
            #pragma unroll
            for (int r = 0; r < 4; ++r)
                O[((size_t)b * NTOK + nb + r) * IN_DIM + dh * 128 + wdq * 64 + t * 16 + lc]
                    = __float2bfloat16(acc[t][r] * sc);
    }
}

// ---------------------------------------------------------------------------
// Kernel B: MFMA flash attention — r18 geometry + LDS pool-union.
//   - 8 waves: group g = wave>>2 handles kv half [g*2048, +2048); QBLK=32,
//     128 q/block (identical instruction counts to round 18)
//   - redC combine buffer OVERLAYS the staging pool (barrier-separated) ->
//     LDS 63488 -> 38912 B -> 4 blocks/CU = 32 waves/CU (2x occupancy)
//   - no-max softmax; K=32 slot-merged PV + ones-column l
// grid 512 (XCD-swizzled); block 512.
// ---------------------------------------------------------------------------
#define KLSZ (64 * 40)
#define VLSZ (32 * 72)
__global__ __launch_bounds__(512) void attn_mfma_kernel(
    const bf16* __restrict__ Q, const bf16* __restrict__ K,
    const bf16* __restrict__ Vt, const float* __restrict__ tgt,
    bf16* __restrict__ Wt)
{
    const int blk = blockIdx.x;
    const int bh  = 2 * (blk & 7) + ((blk >> 3) & 1);
    const int qb  = blk >> 4;               // 0..31
    const int b = bh >> 3, h = bh & 7;
    const int tid  = threadIdx.x;
    const int wave = tid >> 6;
    const int grp  = wave >> 2;             // kv-half
    const int wl   = wave & 3;              // wave within group
    const int lane = tid & 63;
    const int lg = lane >> 4, lc = lane & 15;
    const int qw = qb * 128 + wl * 32;

    // single pool: [grp][buf] K (4 x KLSZ) then [grp][buf] V (4 x VLSZ);
    // redC (4 waves x 64 lanes x 24 f32 = 24576 B) overlays it after the loop
    __shared__ __align__(16) char pool[4 * KLSZ * 2 + 4 * VLSZ * 2];  // 38912 B
    bf16* KLb = (bf16*)pool;
    bf16* VLb = (bf16*)(pool + 4 * KLSZ * 2);
    float* redC = (float*)pool;

    const bf16x8 qfa = *(const bf16x8*)(Q + ((size_t)b * NTOK + qw + lc) * IN_DIM
                                          + h * HDIM + lg * 8);
    const bf16x8 qfb = *(const bf16x8*)(Q + ((size_t)b * NTOK + qw + 16 + lc) * IN_DIM
                                          + h * HDIM + lg * 8);

    bf16x8 ones8;
    #pragma unroll
    for (int i = 0; i < 8; ++i) ((short*)&ones8)[i] = (short)0x3F80;
    const f32x4 z = {0.f, 0.f, 0.f, 0.f};

    const int tg   = tid & 255;             // thread index within group
    const int srow = tg >> 2, sd = (tg & 3) * 8;
    const int vrow = tg >> 3, vch = tg & 7;
    const int kwoff = grp * 2 * KLSZ + srow * 40 + sd;          // +CUR*KLSZ
    const int vwoff = grp * 2 * VLSZ + vrow * 72 + vch * 8;     // +CUR*VLSZ
    const int kroff = grp * 2 * KLSZ + lc * 40 + lg * 8;        // +CUR*KLSZ +t*640
    const int vroff0 = grp * 2 * VLSZ + lc * 72 + lg * 4;       // +CUR*VLSZ +t*16
    const int vroff1 = grp * 2 * VLSZ + (16 + lc) * 72 + lg * 4;

    const bf16* Kp = K  + ((size_t)b * NTOK + grp * 2048 + srow) * IN_DIM + h * HDIM + sd;
    const bf16* Vp = Vt + ((size_t)b * IN_DIM + h * HDIM + vrow) * NTOK + grp * 2048 + vch * 8;

    f32x4 o0a = {0.f,0.f,0.f,0.f}, o1a = {0.f,0.f,0.f,0.f}, ola = {0.f,0.f,0.f,0.f};
    f32x4 o0b = {0.f,0.f,0.f,0.f}, o1b = {0.f,0.f,0.f,0.f}, olb = {0.f,0.f,0.f,0.f};

    bf16x8 kreg = *(const bf16x8*)Kp;
    bf16x8 vreg = *(const bf16x8*)Vp;
    Kp += (size_t)64 * IN_DIM;
    Vp += 64;

#define HALF(CUR)                                                              \
    {                                                                          \
        *(bf16x8*)&KLb[kwoff + (CUR) * KLSZ] = kreg;                           \
        *(bf16x8*)&VLb[vwoff + (CUR) * VLSZ] = vreg;                           \
        kreg = *(const bf16x8*)Kp;                                             \
        vreg = *(const bf16x8*)Vp;                                             \
        Kp += (size_t)64 * IN_DIM;                                             \
        Vp += 64;                                                              \
        __syncthreads();                                                       \
        bf16x8 kf[4];                                                          \
        _Pragma("unroll")                                                      \
        for (int t = 0; t < 4; ++t)                                            \
            kf[t] = *(const bf16x8*)&KLb[kroff + (CUR) * KLSZ + t * 640];      \
        bf16x4 v0[4], v1[4];                                                   \
        _Pragma("unroll")                                                      \
        for (int t = 0; t < 4; ++t) {                                          \
            v0[t] = *(const bf16x4*)&VLb[vroff0 + (CUR) * VLSZ + t * 16];      \
            v1[t] = *(const bf16x4*)&VLb[vroff1 + (CUR) * VLSZ + t * 16];      \
        }                                                                      \
        f32x4 sa[4], sb[4];                                                    \
        __builtin_amdgcn_s_setprio(1);                                         \
        _Pragma("unroll")                                                      \
        for (int t = 0; t < 4; ++t) {                                          \
            sa[t] = __builtin_amdgcn_mfma_f32_16x16x32_bf16(kf[t], qfa, z, 0,0,0); \
            sb[t] = __builtin_amdgcn_mfma_f32_16x16x32_bf16(kf[t], qfb, z, 0,0,0); \
        }                                                                      \
        __builtin_amdgcn_s_setprio(0);                                         \
        _Pragma("unroll")                                                      \
        for (int tcp = 0; tcp < 2; ++tcp) {                                    \
            union { bf16x8 v; uint4 u; } pa, pb;                               \
            pa.u.x = packbf2(fast_exp2(sa[2*tcp][0]),   fast_exp2(sa[2*tcp][1]));   \
            pa.u.y = packbf2(fast_exp2(sa[2*tcp][2]),   fast_exp2(sa[2*tcp][3]));   \
            pa.u.z = packbf2(fast_exp2(sa[2*tcp+1][0]), fast_exp2(sa[2*tcp+1][1])); \
            pa.u.w = packbf2(fast_exp2(sa[2*tcp+1][2]), fast_exp2(sa[2*tcp+1][3])); \
            pb.u.x = packbf2(fast_exp2(sb[2*tcp][0]),   fast_exp2(sb[2*tcp][1]));   \
            pb.u.y = packbf2(fast_exp2(sb[2*tcp][2]),   fast_exp2(sb[2*tcp][3]));   \
            pb.u.z = packbf2(fast_exp2(sb[2*tcp+1][0]), fast_exp2(sb[2*tcp+1][1])); \
            pb.u.w = packbf2(fast_exp2(sb[2*tcp+1][2]), fast_exp2(sb[2*tcp+1][3])); \
            bfrag B0, B1;                                                      \
            B0.h[0] = v0[2*tcp]; B0.h[1] = v0[2*tcp+1];                        \
            B1.h[0] = v1[2*tcp]; B1.h[1] = v1[2*tcp+1];                        \
            __builtin_amdgcn_s_setprio(1);                                     \
            o0a = __builtin_amdgcn_mfma_f32_16x16x32_bf16(pa.v, B0.v, o0a, 0,0,0); \
            o1a = __builtin_amdgcn_mfma_f32_16x16x32_bf16(pa.v, B1.v, o1a, 0,0,0); \
            ola = __builtin_amdgcn_mfma_f32_16x16x32_bf16(pa.v, ones8, ola, 0,0,0); \
            o0b = __builtin_amdgcn_mfma_f32_16x16x32_bf16(pb.v, B0.v, o0b, 0,0,0); \
            o1b = __builtin_amdgcn_mfma_f32_16x16x32_bf16(pb.v, B1.v, o1b, 0,0,0); \
            olb = __builtin_amdgcn_mfma_f32_16x16x32_bf16(pb.v, ones8, olb, 0,0,0); \
            __builtin_amdgcn_s_setprio(0);                                     \
        }                                                                      \
    }

    for (int it = 0; it < NTOK / 256; ++it) {   // 16 iters x 128 kv per group
        HALF(0)
        HALF(1)
    }
#undef HALF

    // ---- combine (pool reuse: all staging reads done after this barrier)
    __syncthreads();
    if (grp) {
        float* d = &redC[(wl * 64 + lane) * 24];
        *(f32x4*)(d + 0)  = o0a;  *(f32x4*)(d + 4)  = o1a;  *(f32x4*)(d + 8)  = ola;
        *(f32x4*)(d + 12) = o0b;  *(f32x4*)(d + 16) = o1b;  *(f32x4*)(d + 20) = olb;
    }
    __syncthreads();
    if (!grp) {
        const float* s = &redC[(wl * 64 + lane) * 24];
        o0a += *(const f32x4*)(s + 0);
        o1a += *(const f32x4*)(s + 4);
        ola += *(const f32x4*)(s + 8);
        o0b += *(const f32x4*)(s + 12);
        o1b += *(const f32x4*)(s + 16);
        olb += *(const f32x4*)(s + 20);

        const float* tga = tgt + ((size_t)b * IN_DIM + h * HDIM + lc) * NTOK + qw + lg * 4;
        float4 r0a = *(const float4*)tga;
        float4 r1a = *(const float4*)(tga + (size_t)16 * NTOK);
        float4 r0b = *(const float4*)(tga + 16);
        float4 r1b = *(const float4*)(tga + (size_t)16 * NTOK + 16);

        bf16* opa = Wt + ((size_t)b * NTOK + qw + lg * 4) * IN_DIM + h * HDIM + lc;
        bf16* opb = opa + (size_t)16 * IN_DIM;
        #pragma unroll
        for (int r = 0; r < 4; ++r) {
            float inva = 1.f / ola[r];
            float invb = 1.f / olb[r];
            opa[(size_t)r * IN_DIM]      = __float2bfloat16(o0a[r] * inva + (&r0a.x)[r]);
            opa[(size_t)r * IN_DIM + 16] = __float2bfloat16(o1a[r] * inva + (&r1a.x)[r]);
            opb[(size_t)r * IN_DIM]      = __float2bfloat16(o0b[r] * invb + (&r0b.x)[r]);
            opb[(size_t)r * IN_DIM + 16] = __float2bfloat16(o1b[r] * invb + (&r1b.x)[r]);
        }
    }
}
#undef KLSZ
#undef VLSZ

// ---------------------------------------------------------------------------
// Kernel C: MFMA output projection.  out[b][n][d] = sum_c A[b][n][c]*Wo[d][c]
// ---------------------------------------------------------------------------
__global__ __launch_bounds__(256) void out_mfma(
    const bf16* __restrict__ A, const float* __restrict__ Wo,
    float* __restrict__ out)
{
    const int dh = blockIdx.y;
    const int b  = blockIdx.x >> 7;
    const int n0 = (blockIdx.x & 127) * 32;

    const int tid = threadIdx.x;
    const int wave = tid >> 6, lane = tid & 63;
    const int lg = lane >> 4, lc = lane & 15;
    const int wn = wave & 1, wdq = wave >> 1;

    __shared__ bf16 As[32 * 260];
    __shared__ bf16 Ws[2][128 * 36];

    {
        const bf16* Ab = A + ((size_t)b * NTOK + n0) * IN_DIM;
        for (int it = 0; it < 4; ++it) {
            int idx = it * 256 + tid;
            int r = idx >> 5, ch = idx & 31;
            bfrag v;
            v.v = *(const bf16x8*)(Ab + (size_t)r * IN_DIM + ch * 8);
            *(bf16x4*)&As[r * 260 + ch * 8]     = v.h[0];
            *(bf16x4*)&As[r * 260 + ch * 8 + 4] = v.h[1];
        }
    }
    const int wd = tid >> 1, wc = (tid & 1) * 16;
    const float* Wbase = Wo + (size_t)(dh * 128 + wd) * IN_DIM + wc;
    {
        float4 a = *(const float4*)(Wbase + 0);
        float4 bb = *(const float4*)(Wbase + 4);
        float4 cc = *(const float4*)(Wbase + 8);
        float4 dd = *(const float4*)(Wbase + 12);
        pack16(a, bb, cc, dd, &Ws[0][wd * 36 + wc]);
    }
    __syncthreads();

    f32x4 acc[4];
    #pragma unroll
    for (int t = 0; t < 4; ++t) acc[t] = f32x4{0.f, 0.f, 0.f, 0.f};

    for (int s = 0; s < 8; ++s) {
        const int c0 = s * 32;
        float4 pa, pb, pc, pd;
        if (s < 7) {
            const float* wn_ = Wbase + (s + 1) * 32;
            pa = *(const float4*)(wn_ + 0);
            pb = *(const float4*)(wn_ + 4);
            pc = *(const float4*)(wn_ + 8);
            pd = *(const float4*)(wn_ + 12);
        }
        bfrag af;
        const bf16* ap = &As[(wn * 16 + lc) * 260 + c0 + lg * 8];
        af.h[0] = *(const bf16x4*)ap;
        af.h[1] = *(const bf16x4*)(ap + 4);
        #pragma unroll
        for (int t = 0; t < 4; ++t) {
            bfrag wf;
            const bf16* wp = &Ws[s & 1][(wdq * 64 + t * 16 + lc) * 36 + lg * 8];
            wf.h[0] = *(const bf16x4*)wp;
            wf.h[1] = *(const bf16x4*)(wp + 4);
            acc[t] = __builtin_amdgcn_mfma_f32_16x16x32_bf16(af.v, wf.v, acc[t], 0, 0, 0);
        }
        if (s < 7) {
            __syncthreads();
            pack16(pa, pb, pc, pd, &Ws[(s + 1) & 1][wd * 36 + wc]);
            __syncthreads();
        }
    }

    const int nb = n0 + wn * 16 + lg * 4;
    #pragma unroll
    for (int t = 0; t < 4; ++t)
        #pragma unroll
        for (int r = 0; r < 4; ++r)
            out[((size_t)b * NTOK + nb + r) * IN_DIM + dh * 128 + wdq * 64 + t * 16 + lc]
                = acc[t][r];
}

// ---------------------------------------------------------------------------
extern "C" void kernel_launch(void* const* d_in, const int* in_sizes, int n_in,
                              void* d_out, int out_size, void* d_ws, size_t ws_size,
                              hipStream_t stream) {
    const float* tgt = (const float*)d_in[0];
    const float* src = (const float*)d_in[1];
    const float* Wq  = (const float*)d_in[2];
    const float* Wk  = (const float*)d_in[3];
    const float* Wv  = (const float*)d_in[4];
    const float* Wo  = (const float*)d_in[5];
    float* out = (float*)d_out;

    const size_t SZ = (size_t)BATCH * NTOK * IN_DIM * sizeof(bf16);  // 4 MiB
    char* w = (char*)d_ws;
    bf16* Qb  = (bf16*)(w);
    bf16* Kb  = (bf16*)(w + SZ);
    bf16* Vtb = (bf16*)(w + 2 * SZ);     // transposed V: [B][C][N]
    bf16* Wt  = (bf16*)(w + 3 * SZ);     // attn out + residual, [B][N][C]

    proj_mfma<<<dim3(256, 3, 2), 256, 0, stream>>>(tgt, src, Wq, Wk, Wv, Qb, Kb, Vtb);

    attn_mfma_kernel<<<512, 512, 0, stream>>>(Qb, Kb, Vtb, tgt, Wt);

    out_mfma<<<dim3(256, 2), 256, 0, stream>>>(Wt, Wo, out);
}